// Round 1
// baseline (753.970 us; speedup 1.0000x reference)
//
#include <hip/hip_runtime.h>
#include <hip/hip_bf16.h>
#include <math.h>

// Problem constants
#define B_SZ 8
#define N_SZ 4096
#define C_SZ 128
#define K_SZ 16
#define NPOINT 1024            // N / POOL_RATE

// FPS config: 256 threads (4 waves, 1 per SIMD), 16 CONTIGUOUS points/thread
#define FPS_T 256
#define FPS_PAIRS 8            // 8 float2-pairs = 16 points per thread

typedef float vf2 __attribute__((ext_vector_type(2)));

// ---------------------------------------------------------------------------
// Wave64 f32 max chain via DPP (full-rate, ~2cyc/stage issue).
// bound_ctrl=1 feeds 0.0 into invalid lanes — distances are >= 0 so 0 is a
// safe identity. After row_shr 1/2/4/8 + row_bcast 15/31, lane 63 = wave max.
// ---------------------------------------------------------------------------
template <int CTRL>
__device__ __forceinline__ float dpp_fmax(float x) {
    int t = __builtin_amdgcn_update_dpp(0, __float_as_int(x), CTRL, 0xF, 0xF, true);
    return fmaxf(x, __int_as_float(t));
}
__device__ __forceinline__ float wave_fmax63(float x) {
    x = dpp_fmax<0x111>(x);  // row_shr:1
    x = dpp_fmax<0x112>(x);  // row_shr:2
    x = dpp_fmax<0x114>(x);  // row_shr:4
    x = dpp_fmax<0x118>(x);  // row_shr:8
    x = dpp_fmax<0x142>(x);  // row_bcast:15
    x = dpp_fmax<0x143>(x);  // row_bcast:31
    return x;                 // valid in lane 63
}

// ---------------------------------------------------------------------------
// Kernel 1: transpose feature_map (B, C, N) -> fmT (B*N, C)
// ---------------------------------------------------------------------------
__global__ void transpose_fm(const float* __restrict__ fm, float* __restrict__ fmT) {
    __shared__ float tile[32][33];
    const int b  = blockIdx.z;
    const int c0 = blockIdx.y * 32;
    const int n0 = blockIdx.x * 32;
    const int tx = threadIdx.x;   // 0..31
    const int ty = threadIdx.y;   // 0..7
    const float* p = fm + (size_t)b * C_SZ * N_SZ;
#pragma unroll
    for (int i = 0; i < 4; i++) {
        tile[ty + i * 8][tx] = p[(size_t)(c0 + ty + i * 8) * N_SZ + n0 + tx];
    }
    __syncthreads();
    float* q = fmT + (size_t)b * N_SZ * C_SZ;
#pragma unroll
    for (int i = 0; i < 4; i++) {
        q[(size_t)(n0 + ty + i * 8) * C_SZ + c0 + tx] = tile[tx][ty + i * 8];
    }
}

// ---------------------------------------------------------------------------
// Kernel 2: FPS, one block (256 threads, 4 waves — one per SIMD) per batch.
// Bit-exact numpy semantics: d=((x-cx)^2+(y-cy)^2)+(z-cz)^2 per-op rounding
// (packed v_pk ops round each half identically to scalar; x-c computed as
// x+(-c) which is bit-identical in IEEE), min then FIRST-index argmax.
//
// Layout: thread tid owns contiguous points [tid*16, tid*16+16). Hence
// within a wave, lane order == point-index order, so the wave argmax is:
//   f32 DPP max chain -> readlane(63) -> ballot(bv==wmax) -> s_ff1 ->
//   readlane(n, first_lane)   (min n among ties, exact)
// Per-lane reverse scan gives min j (= min n) within the lane.
// Cross-wave: packed u64 key (dist<<32)|(4095-n), max => max dist, min n.
// NEW this round:
//  * distance update forced to packed fp32 (v_pk_add/v_pk_mul inline asm):
//    19 -> 11 VALU insts per pair, bit-identical rounding.
//  * winner COORDS travel through LDS alongside the key: each lane
//    speculatively reads sp[bn] (latency hidden under the DPP chain), the
//    wave readlanes the winner's coords, lane0 publishes {key,x,y,z}; after
//    the barrier all 6 LDS reads (keys + 4 coord quads) are independent —
//    removes the dependent post-resolve sp[ci] read (~120 cy) from the
//    critical path.
// One barrier per iteration; no global traffic in the loop.
// ---------------------------------------------------------------------------
__global__ __launch_bounds__(FPS_T) void fps_kernel(
        const float* __restrict__ verts,   // (B, 3, N)
        float* __restrict__ out_vp,        // (B, 3, NPOINT)
        int* __restrict__ cents)           // (B, NPOINT)
{
#pragma clang fp contract(off)
#pragma clang fp reassociate(off)
    __shared__ float4 sp[N_SZ];                       // 64 KB xyz (w unused)
    __shared__ int    scent[NPOINT];                  //  4 KB
    __shared__ alignas(16) unsigned long long ckey[2][4];
    __shared__ alignas(16) float4 ccoord[2][4];

    const int b    = blockIdx.x;
    const int tid  = threadIdx.x;
    const int lane = tid & 63;
    const int wid  = tid >> 6;
    const float* vb = verts + (size_t)b * 3 * N_SZ;

    // stage xyz into LDS (coalesced global loads, conflict-free LDS writes)
    for (int n = tid; n < N_SZ; n += FPS_T) {
        sp[n] = make_float4(vb[n], vb[N_SZ + n], vb[2 * N_SZ + n], 0.0f);
    }

    // contiguous per-thread register copy via coalesced float4 loads
    const float4* vx4 = (const float4*)vb;
    const float4* vy4 = (const float4*)(vb + N_SZ);
    const float4* vz4 = (const float4*)(vb + 2 * N_SZ);
    vf2 px[FPS_PAIRS], py[FPS_PAIRS], pz[FPS_PAIRS], dd[FPS_PAIRS];
#pragma unroll
    for (int k = 0; k < 4; k++) {
        const float4 x = vx4[tid * 4 + k];
        const float4 y = vy4[tid * 4 + k];
        const float4 z = vz4[tid * 4 + k];
        px[2 * k] = (vf2){x.x, x.y}; px[2 * k + 1] = (vf2){x.z, x.w};
        py[2 * k] = (vf2){y.x, y.y}; py[2 * k + 1] = (vf2){y.z, y.w};
        pz[2 * k] = (vf2){z.x, z.y}; pz[2 * k + 1] = (vf2){z.z, z.w};
        dd[2 * k]     = (vf2){1e10f, 1e10f};
        dd[2 * k + 1] = (vf2){1e10f, 1e10f};
    }
    __syncthreads();

    int ci = 0;
    const float4 c0 = sp[0];
    float cx = c0.x, cy = c0.y, cz = c0.z;

    for (int i = 0; i < NPOINT; i++) {
        if (tid == 0) scent[i] = ci;

        // x - c computed as x + (-c): bit-identical in IEEE-754, lets the
        // packed add do the subtraction without modifier syntax.
        const vf2 ncx2 = (vf2){-cx, -cx};
        const vf2 ncy2 = (vf2){-cy, -cy};
        const vf2 ncz2 = (vf2){-cz, -cz};

        float m = -1.0f;                   // running max (v_max3 per pair)
#pragma unroll
        for (int p = 0; p < FPS_PAIRS; p++) {
            vf2 dx, dy, dz, xx, yy, zz, s1, s;
            // forced packed fp32: per-half rounding == scalar ops, and the
            // asm blocks prevent any contraction/reassociation.
            asm("v_pk_add_f32 %0, %1, %2" : "=v"(dx) : "v"(px[p]), "v"(ncx2));
            asm("v_pk_add_f32 %0, %1, %2" : "=v"(dy) : "v"(py[p]), "v"(ncy2));
            asm("v_pk_add_f32 %0, %1, %2" : "=v"(dz) : "v"(pz[p]), "v"(ncz2));
            asm("v_pk_mul_f32 %0, %1, %1" : "=v"(xx) : "v"(dx));
            asm("v_pk_mul_f32 %0, %1, %1" : "=v"(yy) : "v"(dy));
            asm("v_pk_mul_f32 %0, %1, %1" : "=v"(zz) : "v"(dz));
            asm("v_pk_add_f32 %0, %1, %2" : "=v"(s1) : "v"(xx), "v"(yy)); // (x^2+y^2)
            asm("v_pk_add_f32 %0, %1, %2" : "=v"(s)  : "v"(s1), "v"(zz)); // +z^2
            vf2 d;
            d.x = fminf(dd[p].x, s.x);
            d.y = fminf(dd[p].y, s.y);
            dd[p] = d;
            m = fmaxf(m, fmaxf(d.x, d.y)); // folds to v_max3_f32
        }
        const float bv = m;

        // reverse scan: lowest j with dd[j] == bv (max is a selection =>
        // exact bitwise compare); n = tid*16 + j so min j == min n in-lane
        int bj = 0;
#pragma unroll
        for (int j = 15; j >= 0; j--) {
            const float v = (j & 1) ? dd[j >> 1].y : dd[j >> 1].x;
            if (v == bv) bj = j;
        }
        const int bn = (tid << 4) | bj;    // global point index

        // speculative candidate-coords read: every lane fetches its own
        // candidate; the ~120cy LDS latency hides under the DPP chain.
        const float4 cand = sp[bn];

        // wave argmax: f32 chain + ballot + first-lane readback
        const float wm = wave_fmax63(bv);
        const float wmax = __int_as_float(
            __builtin_amdgcn_readlane(__float_as_int(wm), 63));
        const unsigned long long mask = __ballot(bv == wmax);
        const int first = __ffsll(mask) - 1;
        const unsigned nw = (unsigned)__builtin_amdgcn_readlane(bn, first);
        const float wx = __int_as_float(
            __builtin_amdgcn_readlane(__float_as_int(cand.x), first));
        const float wy = __int_as_float(
            __builtin_amdgcn_readlane(__float_as_int(cand.y), first));
        const float wz = __int_as_float(
            __builtin_amdgcn_readlane(__float_as_int(cand.z), first));

        const unsigned long long wkey =
            ((unsigned long long)__float_as_uint(wmax) << 32) |
            (unsigned long long)(4095u - nw);

        const int par = i & 1;
        if (lane == 0) {
            ckey[par][wid]   = wkey;
            ccoord[par][wid] = make_float4(wx, wy, wz, 0.0f);
        }
        __syncthreads();

        // all threads redundantly resolve the 4-way final (no 2nd barrier:
        // parity double-buffer makes the next write race-free). Keys and
        // coords are read with 6 INDEPENDENT ds_reads — one latency, no
        // dependent sp[ci] fetch afterwards.
        const ulonglong2* kb = (const ulonglong2*)(&ckey[par][0]);
        const ulonglong2 k01 = kb[0], k23 = kb[1];
        const float4* qp = &ccoord[par][0];
        const float4 q0 = qp[0], q1 = qp[1], q2 = qp[2], q3 = qp[3];

        // ties impossible across waves (distinct index bits) -> strict >
        const bool t01 = k01.y > k01.x;
        const unsigned long long ka = t01 ? k01.y : k01.x;
        const float ax = t01 ? q1.x : q0.x;
        const float ay = t01 ? q1.y : q0.y;
        const float az = t01 ? q1.z : q0.z;

        const bool t23 = k23.y > k23.x;
        const unsigned long long kc = t23 ? k23.y : k23.x;
        const float bx = t23 ? q3.x : q2.x;
        const float by = t23 ? q3.y : q2.y;
        const float bz = t23 ? q3.z : q2.z;

        const bool tf = kc > ka;
        const unsigned long long kk = tf ? kc : ka;
        ci = (int)(4095u - (unsigned)kk);
        cx = tf ? bx : ax;
        cy = tf ? by : ay;
        cz = tf ? bz : az;
    }
    __syncthreads();

    // epilogue: coalesced writes of cents + vertices_pool
    for (int i = tid; i < NPOINT; i += FPS_T) {
        const int cc = scent[i];
        const float4 v = sp[cc];
        cents[b * NPOINT + i] = cc;
        out_vp[(b * 3 + 0) * NPOINT + i] = v.x;
        out_vp[(b * 3 + 1) * NPOINT + i] = v.y;
        out_vp[(b * 3 + 2) * NPOINT + i] = v.z;
    }
}

// ---------------------------------------------------------------------------
// Kernel 3: gather+maxpool selected rows AND transpose to (B, C, NPOINT).
// 16 waves per block; wave w pools point j0+w (64 lanes x float2 = 128 ch),
// stages the 16x128 tile in LDS, then writes channel-major 64B segments.
// ---------------------------------------------------------------------------
#define GT_J 16
__global__ __launch_bounds__(1024) void pool_gather_t(
        const float* __restrict__ fmT,     // (B*N, C)
        const int* __restrict__ idx,       // (B*N*K), values in [0, B*N)
        const int* __restrict__ cents,     // (B*NPOINT)
        float* __restrict__ out_fp)        // (B, C, NPOINT)
{
    __shared__ float tile[C_SZ][GT_J + 1];
    const int tid  = threadIdx.x;
    const int lane = tid & 63;
    const int w    = tid >> 6;
    const int j0   = blockIdx.x * GT_J;    // global pooled-point base
    const int gp   = j0 + w;
    const int b    = gp >> 10;             // NPOINT = 1024
    const int ci   = cents[gp];
    const int* ip  = idx + ((size_t)(b * N_SZ + ci)) * K_SZ;
    const float2* src = (const float2*)fmT;

    float2 acc = make_float2(-INFINITY, -INFINITY);
#pragma unroll
    for (int k = 0; k < K_SZ; k++) {
        const int p = ip[k];
        const float2 v = src[(size_t)p * (C_SZ / 2) + lane];
        acc.x = fmaxf(acc.x, v.x);
        acc.y = fmaxf(acc.y, v.y);
    }
    tile[2 * lane][w]     = acc.x;
    tile[2 * lane + 1][w] = acc.y;
    __syncthreads();

    float* q = out_fp + (size_t)b * C_SZ * NPOINT + (j0 & (NPOINT - 1));
#pragma unroll
    for (int it = 0; it < 2; it++) {
        const int e  = tid + it * 1024;
        const int c  = e >> 4;
        const int jj = e & (GT_J - 1);
        q[(size_t)c * NPOINT + jj] = tile[c][jj];
    }
}

// ---------------------------------------------------------------------------
extern "C" void kernel_launch(void* const* d_in, const int* in_sizes, int n_in,
                              void* d_out, int out_size, void* d_ws, size_t ws_size,
                              hipStream_t stream) {
    const float* verts = (const float*)d_in[0];   // (B,3,N) f32
    const float* fm    = (const float*)d_in[1];   // (B,C,N) f32
    const int*   idx   = (const int*)d_in[2];     // (B*N*K) i32

    float* out    = (float*)d_out;
    float* out_vp = out;                               // B*3*NPOINT = 24576
    float* out_fp = out + (size_t)B_SZ * 3 * NPOINT;   // B*C*NPOINT

    char* ws = (char*)d_ws;
    float* fmT   = (float*)ws;                                     // 16 MB
    int*   cents = (int*)(ws + (size_t)B_SZ * N_SZ * C_SZ * 4);    // 32 KB

    dim3 tb(32, 8);
    transpose_fm<<<dim3(N_SZ / 32, C_SZ / 32, B_SZ), tb, 0, stream>>>(fm, fmT);
    fps_kernel<<<B_SZ, FPS_T, 0, stream>>>(verts, out_vp, cents);
    pool_gather_t<<<(B_SZ * NPOINT) / GT_J, 1024, 0, stream>>>(fmT, idx, cents, out_fp);
}

// Round 2
// 664.221 us; speedup vs baseline: 1.1351x; 1.1351x over previous
//
#include <hip/hip_runtime.h>
#include <hip/hip_bf16.h>
#include <math.h>

// Problem constants
#define B_SZ 8
#define N_SZ 4096
#define C_SZ 128
#define K_SZ 16
#define NPOINT 1024            // N / POOL_RATE

// FPS config: 256 threads (4 waves, 1 per SIMD), 16 CONTIGUOUS points/thread
#define FPS_T 256
#define FPS_PAIRS 8            // 8 float2-pairs = 16 points per thread

typedef float vf2 __attribute__((ext_vector_type(2)));

// ---------------------------------------------------------------------------
// Wave64 f32 max chain via DPP (full-rate, ~2cyc/stage issue).
// bound_ctrl=1 feeds 0.0 into invalid lanes — distances are >= 0 so 0 is a
// safe identity. After row_shr 1/2/4/8 + row_bcast 15/31, lane 63 = wave max.
// ---------------------------------------------------------------------------
template <int CTRL>
__device__ __forceinline__ float dpp_fmax(float x) {
    int t = __builtin_amdgcn_update_dpp(0, __float_as_int(x), CTRL, 0xF, 0xF, true);
    return fmaxf(x, __int_as_float(t));
}
__device__ __forceinline__ float wave_fmax63(float x) {
    x = dpp_fmax<0x111>(x);  // row_shr:1
    x = dpp_fmax<0x112>(x);  // row_shr:2
    x = dpp_fmax<0x114>(x);  // row_shr:4
    x = dpp_fmax<0x118>(x);  // row_shr:8
    x = dpp_fmax<0x142>(x);  // row_bcast:15
    x = dpp_fmax<0x143>(x);  // row_bcast:31
    return x;                 // valid in lane 63
}
__device__ __forceinline__ unsigned long long kmax2(unsigned long long a,
                                                   unsigned long long b) {
    return a > b ? a : b;
}

// ---------------------------------------------------------------------------
// Kernel 1: transpose feature_map (B, C, N) -> fmT (B*N, C)
// ---------------------------------------------------------------------------
__global__ void transpose_fm(const float* __restrict__ fm, float* __restrict__ fmT) {
    __shared__ float tile[32][33];
    const int b  = blockIdx.z;
    const int c0 = blockIdx.y * 32;
    const int n0 = blockIdx.x * 32;
    const int tx = threadIdx.x;   // 0..31
    const int ty = threadIdx.y;   // 0..7
    const float* p = fm + (size_t)b * C_SZ * N_SZ;
#pragma unroll
    for (int i = 0; i < 4; i++) {
        tile[ty + i * 8][tx] = p[(size_t)(c0 + ty + i * 8) * N_SZ + n0 + tx];
    }
    __syncthreads();
    float* q = fmT + (size_t)b * N_SZ * C_SZ;
#pragma unroll
    for (int i = 0; i < 4; i++) {
        q[(size_t)(n0 + ty + i * 8) * C_SZ + c0 + tx] = tile[tx][ty + i * 8];
    }
}

// ---------------------------------------------------------------------------
// Kernel 2: FPS, one block (256 threads, 4 waves — one per SIMD) per batch.
// Bit-exact numpy semantics: d=((x-cx)^2+(y-cy)^2)+(z-cz)^2 per-op rounding
// (packed v_pk ops round each half identically to scalar; x-c computed as
// x+(-c) which is bit-identical in IEEE), min then FIRST-index argmax.
//
// Layout: thread tid owns contiguous points [tid*16, tid*16+16). Hence
// within a wave, lane order == point-index order, so the wave argmax is:
//   f32 DPP max chain -> readlane(63) -> ballot(bv==wmax) -> s_ff1 ->
//   readlane(n, first_lane)   (min n among ties, exact)
// Per-lane reverse scan gives min j (= min n) within the lane.
// Cross-wave: packed u64 key (dist<<32)|(4095-n), max => max dist, min n.
//
// Round-2 post-mortem note: round 1's per-lane speculative sp[bn] scatter
// read cost 422k LDS bank-conflict cycles (~176us) — reverted. Resolve is
// round-0's structure: post-barrier ckey read + kmax tree + BROADCAST
// sp[ci] read (all lanes same address => conflict-free). The packed
// v_pk_add/v_pk_mul distance update (19 -> 11 VALU insts/pair) is kept.
// One barrier per iteration; no global traffic in the loop.
// ---------------------------------------------------------------------------
__global__ __launch_bounds__(FPS_T) void fps_kernel(
        const float* __restrict__ verts,   // (B, 3, N)
        float* __restrict__ out_vp,        // (B, 3, NPOINT)
        int* __restrict__ cents)           // (B, NPOINT)
{
#pragma clang fp contract(off)
#pragma clang fp reassociate(off)
    __shared__ float4 sp[N_SZ];                       // 64 KB xyz (w unused)
    __shared__ int    scent[NPOINT];                  //  4 KB
    __shared__ alignas(16) unsigned long long ckey[2][4];

    const int b    = blockIdx.x;
    const int tid  = threadIdx.x;
    const int lane = tid & 63;
    const int wid  = tid >> 6;
    const float* vb = verts + (size_t)b * 3 * N_SZ;

    // stage xyz into LDS (coalesced global loads, conflict-free LDS writes)
    for (int n = tid; n < N_SZ; n += FPS_T) {
        sp[n] = make_float4(vb[n], vb[N_SZ + n], vb[2 * N_SZ + n], 0.0f);
    }

    // contiguous per-thread register copy via coalesced float4 loads
    const float4* vx4 = (const float4*)vb;
    const float4* vy4 = (const float4*)(vb + N_SZ);
    const float4* vz4 = (const float4*)(vb + 2 * N_SZ);
    vf2 px[FPS_PAIRS], py[FPS_PAIRS], pz[FPS_PAIRS], dd[FPS_PAIRS];
#pragma unroll
    for (int k = 0; k < 4; k++) {
        const float4 x = vx4[tid * 4 + k];
        const float4 y = vy4[tid * 4 + k];
        const float4 z = vz4[tid * 4 + k];
        px[2 * k] = (vf2){x.x, x.y}; px[2 * k + 1] = (vf2){x.z, x.w};
        py[2 * k] = (vf2){y.x, y.y}; py[2 * k + 1] = (vf2){y.z, y.w};
        pz[2 * k] = (vf2){z.x, z.y}; pz[2 * k + 1] = (vf2){z.z, z.w};
        dd[2 * k]     = (vf2){1e10f, 1e10f};
        dd[2 * k + 1] = (vf2){1e10f, 1e10f};
    }
    __syncthreads();

    int ci = 0;
    const float4 c0 = sp[0];
    float cx = c0.x, cy = c0.y, cz = c0.z;

    for (int i = 0; i < NPOINT; i++) {
        if (tid == 0) scent[i] = ci;

        // x - c computed as x + (-c): bit-identical in IEEE-754, lets the
        // packed add do the subtraction without modifier syntax.
        const vf2 ncx2 = (vf2){-cx, -cx};
        const vf2 ncy2 = (vf2){-cy, -cy};
        const vf2 ncz2 = (vf2){-cz, -cz};

        float m = -1.0f;                   // running max (v_max3 per pair)
#pragma unroll
        for (int p = 0; p < FPS_PAIRS; p++) {
            vf2 dx, dy, dz, xx, yy, zz, s1, s;
            // forced packed fp32: per-half rounding == scalar ops, and the
            // asm blocks prevent any contraction/reassociation.
            asm("v_pk_add_f32 %0, %1, %2" : "=v"(dx) : "v"(px[p]), "v"(ncx2));
            asm("v_pk_add_f32 %0, %1, %2" : "=v"(dy) : "v"(py[p]), "v"(ncy2));
            asm("v_pk_add_f32 %0, %1, %2" : "=v"(dz) : "v"(pz[p]), "v"(ncz2));
            asm("v_pk_mul_f32 %0, %1, %1" : "=v"(xx) : "v"(dx));
            asm("v_pk_mul_f32 %0, %1, %1" : "=v"(yy) : "v"(dy));
            asm("v_pk_mul_f32 %0, %1, %1" : "=v"(zz) : "v"(dz));
            asm("v_pk_add_f32 %0, %1, %2" : "=v"(s1) : "v"(xx), "v"(yy)); // (x^2+y^2)
            asm("v_pk_add_f32 %0, %1, %2" : "=v"(s)  : "v"(s1), "v"(zz)); // +z^2
            vf2 d;
            d.x = fminf(dd[p].x, s.x);
            d.y = fminf(dd[p].y, s.y);
            dd[p] = d;
            m = fmaxf(m, fmaxf(d.x, d.y)); // folds to v_max3_f32
        }
        const float bv = m;

        // reverse scan: lowest j with dd[j] == bv (max is a selection =>
        // exact bitwise compare); n = tid*16 + j so min j == min n in-lane
        int bj = 0;
#pragma unroll
        for (int j = 15; j >= 0; j--) {
            const float v = (j & 1) ? dd[j >> 1].y : dd[j >> 1].x;
            if (v == bv) bj = j;
        }
        const int bn = (tid << 4) | bj;    // global point index

        // wave argmax: f32 chain + ballot + first-lane readback
        const float wm = wave_fmax63(bv);
        const float wmax = __int_as_float(
            __builtin_amdgcn_readlane(__float_as_int(wm), 63));
        const unsigned long long mask = __ballot(bv == wmax);
        const int first = __ffsll(mask) - 1;
        const unsigned nw = (unsigned)__builtin_amdgcn_readlane(bn, first);

        const unsigned long long wkey =
            ((unsigned long long)__float_as_uint(wmax) << 32) |
            (unsigned long long)(4095u - nw);

        const int par = i & 1;
        if (lane == 0) ckey[par][wid] = wkey;
        __syncthreads();

        // all threads redundantly resolve the 4-way final (no 2nd barrier:
        // parity double-buffer makes the next write race-free)
        const ulonglong2* kb = (const ulonglong2*)(&ckey[par][0]);
        const ulonglong2 k01 = kb[0], k23 = kb[1];
        const unsigned long long kk =
            kmax2(kmax2(k01.x, k01.y), kmax2(k23.x, k23.y));

        ci = (int)(4095u - (unsigned)kk);
        const float4 c = sp[ci];           // broadcast read: conflict-free
        cx = c.x; cy = c.y; cz = c.z;
    }
    __syncthreads();

    // epilogue: coalesced writes of cents + vertices_pool
    for (int i = tid; i < NPOINT; i += FPS_T) {
        const int cc = scent[i];
        const float4 v = sp[cc];
        cents[b * NPOINT + i] = cc;
        out_vp[(b * 3 + 0) * NPOINT + i] = v.x;
        out_vp[(b * 3 + 1) * NPOINT + i] = v.y;
        out_vp[(b * 3 + 2) * NPOINT + i] = v.z;
    }
}

// ---------------------------------------------------------------------------
// Kernel 3: gather+maxpool selected rows AND transpose to (B, C, NPOINT).
// 16 waves per block; wave w pools point j0+w (64 lanes x float2 = 128 ch),
// stages the 16x128 tile in LDS, then writes channel-major 64B segments.
// ---------------------------------------------------------------------------
#define GT_J 16
__global__ __launch_bounds__(1024) void pool_gather_t(
        const float* __restrict__ fmT,     // (B*N, C)
        const int* __restrict__ idx,       // (B*N*K), values in [0, B*N)
        const int* __restrict__ cents,     // (B*NPOINT)
        float* __restrict__ out_fp)        // (B, C, NPOINT)
{
    __shared__ float tile[C_SZ][GT_J + 1];
    const int tid  = threadIdx.x;
    const int lane = tid & 63;
    const int w    = tid >> 6;
    const int j0   = blockIdx.x * GT_J;    // global pooled-point base
    const int gp   = j0 + w;
    const int b    = gp >> 10;             // NPOINT = 1024
    const int ci   = cents[gp];
    const int* ip  = idx + ((size_t)(b * N_SZ + ci)) * K_SZ;
    const float2* src = (const float2*)fmT;

    float2 acc = make_float2(-INFINITY, -INFINITY);
#pragma unroll
    for (int k = 0; k < K_SZ; k++) {
        const int p = ip[k];
        const float2 v = src[(size_t)p * (C_SZ / 2) + lane];
        acc.x = fmaxf(acc.x, v.x);
        acc.y = fmaxf(acc.y, v.y);
    }
    tile[2 * lane][w]     = acc.x;
    tile[2 * lane + 1][w] = acc.y;
    __syncthreads();

    float* q = out_fp + (size_t)b * C_SZ * NPOINT + (j0 & (NPOINT - 1));
#pragma unroll
    for (int it = 0; it < 2; it++) {
        const int e  = tid + it * 1024;
        const int c  = e >> 4;
        const int jj = e & (GT_J - 1);
        q[(size_t)c * NPOINT + jj] = tile[c][jj];
    }
}

// ---------------------------------------------------------------------------
extern "C" void kernel_launch(void* const* d_in, const int* in_sizes, int n_in,
                              void* d_out, int out_size, void* d_ws, size_t ws_size,
                              hipStream_t stream) {
    const float* verts = (const float*)d_in[0];   // (B,3,N) f32
    const float* fm    = (const float*)d_in[1];   // (B,C,N) f32
    const int*   idx   = (const int*)d_in[2];     // (B*N*K) i32

    float* out    = (float*)d_out;
    float* out_vp = out;                               // B*3*NPOINT = 24576
    float* out_fp = out + (size_t)B_SZ * 3 * NPOINT;   // B*C*NPOINT

    char* ws = (char*)d_ws;
    float* fmT   = (float*)ws;                                     // 16 MB
    int*   cents = (int*)(ws + (size_t)B_SZ * N_SZ * C_SZ * 4);    // 32 KB

    dim3 tb(32, 8);
    transpose_fm<<<dim3(N_SZ / 32, C_SZ / 32, B_SZ), tb, 0, stream>>>(fm, fmT);
    fps_kernel<<<B_SZ, FPS_T, 0, stream>>>(verts, out_vp, cents);
    pool_gather_t<<<(B_SZ * NPOINT) / GT_J, 1024, 0, stream>>>(fmT, idx, cents, out_fp);
}

// Round 3
// 624.017 us; speedup vs baseline: 1.2083x; 1.0644x over previous
//
#include <hip/hip_runtime.h>
#include <hip/hip_bf16.h>
#include <math.h>

// Problem constants
#define B_SZ 8
#define N_SZ 4096
#define C_SZ 128
#define K_SZ 16
#define NPOINT 1024            // N / POOL_RATE

// FPS config: 256 threads (4 waves, 1 per SIMD), 16 CONTIGUOUS points/thread
#define FPS_T 256
#define FPS_PAIRS 8            // 8 float2-pairs = 16 points per thread

typedef float vf2 __attribute__((ext_vector_type(2)));

// ---------------------------------------------------------------------------
// Wave64 f32 max chain via DPP (full-rate, ~2cyc/stage issue).
// bound_ctrl=1 feeds 0.0 into invalid lanes — distances are >= 0 so 0 is a
// safe identity. After row_shr 1/2/4/8 + row_bcast 15/31, lane 63 = wave max.
// ---------------------------------------------------------------------------
template <int CTRL>
__device__ __forceinline__ float dpp_fmax(float x) {
    int t = __builtin_amdgcn_update_dpp(0, __float_as_int(x), CTRL, 0xF, 0xF, true);
    return fmaxf(x, __int_as_float(t));
}
__device__ __forceinline__ float wave_fmax63(float x) {
    x = dpp_fmax<0x111>(x);  // row_shr:1
    x = dpp_fmax<0x112>(x);  // row_shr:2
    x = dpp_fmax<0x114>(x);  // row_shr:4
    x = dpp_fmax<0x118>(x);  // row_shr:8
    x = dpp_fmax<0x142>(x);  // row_bcast:15
    x = dpp_fmax<0x143>(x);  // row_bcast:31
    return x;                 // valid in lane 63
}
__device__ __forceinline__ unsigned long long kmax2(unsigned long long a,
                                                   unsigned long long b) {
    return a > b ? a : b;
}

// ---------------------------------------------------------------------------
// Merged kernel: blocks 0..7 run FPS (one per batch); blocks 8..8+4095 run
// the feature-map transpose (B,C,N)->(B*N,C) on the otherwise-idle CUs.
// The two jobs touch disjoint data; transpose traffic (~32 MB) drains in
// ~10 us under the 530 us FPS shadow, saving its serial wall + one launch.
//
// FPS notes (bit-exact numpy semantics, d=((x-cx)^2+(y-cy)^2)+(z-cz)^2 with
// per-op rounding — contract/reassoc off — min then FIRST-index argmax):
//  * thread tid owns contiguous points [tid*16, tid*16+16): lane order ==
//    point order, so wave argmax = f32 DPP chain -> readlane(63) ->
//    ballot(bv==wmax) -> s_ff1 -> readlane(bn, first) (min n among ties).
//  * per-lane reverse scan gives min j within the lane (exact bitwise ==,
//    max is a selection).
//  * cross-wave: packed u64 key (dist<<32)|(4095-n); max => max d, min n.
//    Parity double-buffered ckey => ONE barrier per iteration.
//  * post-barrier sp[ci] read is a BROADCAST (all lanes same address) —
//    conflict-free. (Round-1's per-lane scatter read cost 422k conflict
//    cycles; round-2's v_pk asm was ALU-throughput-neutral — pk f32 is
//    4-cyc occupancy vs 2-cyc scalar, same FLOPs/cyc — plus marshaling
//    moves. Both reverted; distance loop below is round-0 verbatim.)
// ---------------------------------------------------------------------------
union SMem {
    struct {
        float4 sp[N_SZ];                       // 64 KB xyz (w unused)
        int    scent[NPOINT];                  //  4 KB
        unsigned long long ckey[2][4];         // parity double-buffer
    } f;
    float tile[32][33];                        // transpose tile
};

__global__ __launch_bounds__(FPS_T) void fps_tr_kernel(
        const float* __restrict__ verts,   // (B, 3, N)
        const float* __restrict__ fm,      // (B, C, N)
        float* __restrict__ out_vp,        // (B, 3, NPOINT)
        int* __restrict__ cents,           // (B, NPOINT)
        float* __restrict__ fmT)           // (B*N, C)
{
#pragma clang fp contract(off)
#pragma clang fp reassociate(off)
    __shared__ SMem sm;
    const int tid = threadIdx.x;

    if (blockIdx.x >= B_SZ) {
        // ---------------- transpose path (4096 blocks) ----------------
        const int bid = blockIdx.x - B_SZ;       // original grid (128,4,8)
        const int n0 = (bid & 127) * 32;
        const int c0 = ((bid >> 7) & 3) * 32;
        const int b  = bid >> 9;
        const int tx = tid & 31;                 // 0..31
        const int ty = tid >> 5;                 // 0..7
        const float* p = fm + (size_t)b * C_SZ * N_SZ;
#pragma unroll
        for (int i = 0; i < 4; i++) {
            sm.tile[ty + i * 8][tx] =
                p[(size_t)(c0 + ty + i * 8) * N_SZ + n0 + tx];
        }
        __syncthreads();
        float* q = fmT + (size_t)b * N_SZ * C_SZ;
#pragma unroll
        for (int i = 0; i < 4; i++) {
            q[(size_t)(n0 + ty + i * 8) * C_SZ + c0 + tx] =
                sm.tile[tx][ty + i * 8];
        }
        return;
    }

    // ------------------------- FPS path (8 blocks) -------------------------
    float4* sp   = sm.f.sp;
    int*    scnt = sm.f.scent;

    const int b    = blockIdx.x;
    const int lane = tid & 63;
    const int wid  = tid >> 6;
    const float* vb = verts + (size_t)b * 3 * N_SZ;

    // stage xyz into LDS (coalesced global loads, conflict-free LDS writes)
    for (int n = tid; n < N_SZ; n += FPS_T) {
        sp[n] = make_float4(vb[n], vb[N_SZ + n], vb[2 * N_SZ + n], 0.0f);
    }

    // contiguous per-thread register copy via coalesced float4 loads
    const float4* vx4 = (const float4*)vb;
    const float4* vy4 = (const float4*)(vb + N_SZ);
    const float4* vz4 = (const float4*)(vb + 2 * N_SZ);
    vf2 px[FPS_PAIRS], py[FPS_PAIRS], pz[FPS_PAIRS], dd[FPS_PAIRS];
#pragma unroll
    for (int k = 0; k < 4; k++) {
        const float4 x = vx4[tid * 4 + k];
        const float4 y = vy4[tid * 4 + k];
        const float4 z = vz4[tid * 4 + k];
        px[2 * k] = (vf2){x.x, x.y}; px[2 * k + 1] = (vf2){x.z, x.w};
        py[2 * k] = (vf2){y.x, y.y}; py[2 * k + 1] = (vf2){y.z, y.w};
        pz[2 * k] = (vf2){z.x, z.y}; pz[2 * k + 1] = (vf2){z.z, z.w};
        dd[2 * k]     = (vf2){1e10f, 1e10f};
        dd[2 * k + 1] = (vf2){1e10f, 1e10f};
    }
    __syncthreads();

    int ci = 0;
    const float4 c0 = sp[0];
    float cx = c0.x, cy = c0.y, cz = c0.z;

    for (int i = 0; i < NPOINT; i++) {
        if (tid == 0) scnt[i] = ci;

        const vf2 cx2 = (vf2){cx, cx};
        const vf2 cy2 = (vf2){cy, cy};
        const vf2 cz2 = (vf2){cz, cz};

        float m = -1.0f;                   // running max (v_max3 per pair)
#pragma unroll
        for (int p = 0; p < FPS_PAIRS; p++) {
            const vf2 dx = px[p] - cx2;
            const vf2 dy = py[p] - cy2;
            const vf2 dz = pz[p] - cz2;
            vf2 s = dx * dx + dy * dy;     // contract off => mul,mul,add
            s = s + dz * dz;               // ((x^2+y^2)+z^2) order
            vf2 d;
            d.x = fminf(dd[p].x, s.x);
            d.y = fminf(dd[p].y, s.y);
            dd[p] = d;
            m = fmaxf(m, fmaxf(d.x, d.y)); // folds to v_max3_f32
        }
        const float bv = m;

        // reverse scan: lowest j with dd[j] == bv (max is a selection =>
        // exact bitwise compare); n = tid*16 + j so min j == min n in-lane
        int bj = 0;
#pragma unroll
        for (int j = 15; j >= 0; j--) {
            const float v = (j & 1) ? dd[j >> 1].y : dd[j >> 1].x;
            if (v == bv) bj = j;
        }
        const int bn = (tid << 4) | bj;    // global point index

        // wave argmax: f32 chain + ballot + first-lane readback
        const float wm = wave_fmax63(bv);
        const float wmax = __int_as_float(
            __builtin_amdgcn_readlane(__float_as_int(wm), 63));
        const unsigned long long mask = __ballot(bv == wmax);
        const int first = __ffsll(mask) - 1;
        const unsigned nw = (unsigned)__builtin_amdgcn_readlane(bn, first);

        const unsigned long long wkey =
            ((unsigned long long)__float_as_uint(wmax) << 32) |
            (unsigned long long)(4095u - nw);

        const int par = i & 1;
        if (lane == 0) sm.f.ckey[par][wid] = wkey;
        __syncthreads();

        // all threads redundantly resolve the 4-way final (no 2nd barrier:
        // parity double-buffer makes the next write race-free)
        const ulonglong2* kb = (const ulonglong2*)(&sm.f.ckey[par][0]);
        const ulonglong2 k01 = kb[0], k23 = kb[1];
        const unsigned long long kk =
            kmax2(kmax2(k01.x, k01.y), kmax2(k23.x, k23.y));

        ci = (int)(4095u - (unsigned)kk);
        const float4 c = sp[ci];           // broadcast read: conflict-free
        cx = c.x; cy = c.y; cz = c.z;
    }
    __syncthreads();

    // epilogue: coalesced writes of cents + vertices_pool
    for (int i = tid; i < NPOINT; i += FPS_T) {
        const int cc = scnt[i];
        const float4 v = sp[cc];
        cents[b * NPOINT + i] = cc;
        out_vp[(b * 3 + 0) * NPOINT + i] = v.x;
        out_vp[(b * 3 + 1) * NPOINT + i] = v.y;
        out_vp[(b * 3 + 2) * NPOINT + i] = v.z;
    }
}

// ---------------------------------------------------------------------------
// Kernel 2: gather+maxpool selected rows AND transpose to (B, C, NPOINT).
// 16 waves per block; wave w pools point j0+w (64 lanes x float2 = 128 ch),
// stages the 16x128 tile in LDS, then writes channel-major 64B segments.
// ---------------------------------------------------------------------------
#define GT_J 16
__global__ __launch_bounds__(1024) void pool_gather_t(
        const float* __restrict__ fmT,     // (B*N, C)
        const int* __restrict__ idx,       // (B*N*K), values in [0, B*N)
        const int* __restrict__ cents,     // (B*NPOINT)
        float* __restrict__ out_fp)        // (B, C, NPOINT)
{
    __shared__ float tile[C_SZ][GT_J + 1];
    const int tid  = threadIdx.x;
    const int lane = tid & 63;
    const int w    = tid >> 6;
    const int j0   = blockIdx.x * GT_J;    // global pooled-point base
    const int gp   = j0 + w;
    const int b    = gp >> 10;             // NPOINT = 1024
    const int ci   = cents[gp];
    const int* ip  = idx + ((size_t)(b * N_SZ + ci)) * K_SZ;
    const float2* src = (const float2*)fmT;

    float2 acc = make_float2(-INFINITY, -INFINITY);
#pragma unroll
    for (int k = 0; k < K_SZ; k++) {
        const int p = ip[k];
        const float2 v = src[(size_t)p * (C_SZ / 2) + lane];
        acc.x = fmaxf(acc.x, v.x);
        acc.y = fmaxf(acc.y, v.y);
    }
    tile[2 * lane][w]     = acc.x;
    tile[2 * lane + 1][w] = acc.y;
    __syncthreads();

    float* q = out_fp + (size_t)b * C_SZ * NPOINT + (j0 & (NPOINT - 1));
#pragma unroll
    for (int it = 0; it < 2; it++) {
        const int e  = tid + it * 1024;
        const int c  = e >> 4;
        const int jj = e & (GT_J - 1);
        q[(size_t)c * NPOINT + jj] = tile[c][jj];
    }
}

// ---------------------------------------------------------------------------
extern "C" void kernel_launch(void* const* d_in, const int* in_sizes, int n_in,
                              void* d_out, int out_size, void* d_ws, size_t ws_size,
                              hipStream_t stream) {
    const float* verts = (const float*)d_in[0];   // (B,3,N) f32
    const float* fm    = (const float*)d_in[1];   // (B,C,N) f32
    const int*   idx   = (const int*)d_in[2];     // (B*N*K) i32

    float* out    = (float*)d_out;
    float* out_vp = out;                               // B*3*NPOINT = 24576
    float* out_fp = out + (size_t)B_SZ * 3 * NPOINT;   // B*C*NPOINT

    char* ws = (char*)d_ws;
    float* fmT   = (float*)ws;                                     // 16 MB
    int*   cents = (int*)(ws + (size_t)B_SZ * N_SZ * C_SZ * 4);    // 32 KB

    // FPS blocks 0..7 + transpose blocks 8..4103 in one dispatch: transpose
    // streams on the 248 CUs FPS doesn't use, fully hidden under FPS.
    fps_tr_kernel<<<B_SZ + (N_SZ / 32) * (C_SZ / 32) * B_SZ, FPS_T, 0, stream>>>(
        verts, fm, out_vp, cents, fmT);
    pool_gather_t<<<(B_SZ * NPOINT) / GT_J, 1024, 0, stream>>>(fmT, idx, cents, out_fp);
}